// Round 8
// baseline (367.218 us; speedup 1.0000x reference)
//
#include <hip/hip_runtime.h>
#include <hip/hip_bf16.h>
#include <math.h>

#define DIMV 512
#define NTOK 16384   // B*P*N = 2*8*1024
#define NSEQ 1024
#define HEADSV 8
#define PPV 8
#define DHEAD 64
#define QKVW 1536
#define HIDV 2048
#define SC2 0.18033688011112042f   // 0.125 * log2(e)

typedef unsigned short ushort;
typedef unsigned int uint;
typedef __attribute__((ext_vector_type(8))) short short8;
typedef __attribute__((ext_vector_type(8))) unsigned short ushort8;
typedef __attribute__((ext_vector_type(4))) unsigned short ushortx4;
typedef __attribute__((ext_vector_type(4))) float floatx4;

__device__ __forceinline__ float bf2f(ushort u){
  union { unsigned int i; float f; } c; c.i = ((unsigned int)u) << 16; return c.f;
}
// fast RNE f32->bf16 (finite values; no NaN branch): 3 VALU
__device__ __forceinline__ ushort f2bf(float f){
  union { float f; unsigned int i; } c; c.f = f;
  unsigned int u = c.i + 0x7fffu + ((c.i >> 16) & 1u);
  return (ushort)(u >> 16);
}
__device__ __forceinline__ void async_copy16(const void* gptr, void* lptr){
  __builtin_amdgcn_global_load_lds((const __attribute__((address_space(1))) void*)gptr,
                                   (__attribute__((address_space(3))) void*)lptr, 16, 0, 0);
}
// tanh-form GELU via one v_exp_f32: x * sigmoid(1.5957691x + 0.0713548x^3)
__device__ __forceinline__ float fast_gelu(float x){
  float u = x * (2.3022084f + 0.1029435f * x * x);   // (2u)*log2(e)
  return x * __builtin_amdgcn_rcpf(1.f + exp2f(-u));
}

__device__ __forceinline__ void wave_reduce2(float& a, float& b){
  #pragma unroll
  for (int off = 32; off > 0; off >>= 1){
    a += __shfl_down(a, off, 64);
    b += __shfl_down(b, off, 64);
  }
}

// ---- fused prep kernel: LN (blocks [0,16384)) + 4 weight transposes ----
__device__ __forceinline__ void wtrans_body(const float* __restrict__ W,
    __hip_bfloat16* __restrict__ Wt, int K, int N, int bx, int by, int t,
    float* tile /* 32*33 */){
  int bn = bx * 32, bk = by * 32;
  int tx = t & 31, ty = t >> 5;
  #pragma unroll
  for (int i = 0; i < 32; i += 8)
    tile[(ty + i) * 33 + tx] = W[(size_t)(bk + ty + i) * N + bn + tx];
  __syncthreads();
  #pragma unroll
  for (int i = 0; i < 32; i += 8)
    Wt[(size_t)(bn + ty + i) * K + bk + tx] = __float2bfloat16(tile[tx * 33 + ty + i]);
}

__global__ __launch_bounds__(256) void prep_kernel(const float* __restrict__ x,
    const float* __restrict__ w0, const float* __restrict__ b0,
    const float* __restrict__ w1ln, const float* __restrict__ b1ln,
    __hip_bfloat16* __restrict__ x1, __hip_bfloat16* __restrict__ h,
    const float* __restrict__ wqkv, __hip_bfloat16* __restrict__ wqkvT,
    const float* __restrict__ wo,   __hip_bfloat16* __restrict__ woT,
    const float* __restrict__ w1,   __hip_bfloat16* __restrict__ w1T,
    const float* __restrict__ w2,   __hip_bfloat16* __restrict__ w2T){
  __shared__ float smem[32 * 33];
  int bid = blockIdx.x;
  int t = threadIdx.x;
  if (bid >= NTOK){
    int r = bid - NTOK;
    if (r < 768)        wtrans_body(wqkv, wqkvT, 512, 1536, r % 48, r / 48, t, smem);
    else if (r < 1024){ r -= 768;  wtrans_body(wo, woT, 512, 512,  r % 16, r / 16, t, smem); }
    else if (r < 2048){ r -= 1024; wtrans_body(w1, w1T, 512, 2048, r % 64, r / 64, t, smem); }
    else             { r -= 2048; wtrans_body(w2, w2T, 2048, 512, r % 16, r / 16, t, smem); }
    return;
  }
  // ---- double LN ----
  float* sm = smem;
  size_t row = bid;
  const float2* xr = (const float2*)(x + row * DIMV);
  float2 v = xr[t];
  float s = v.x + v.y;
  float sq = v.x * v.x + v.y * v.y;
  wave_reduce2(s, sq);
  int wid = t >> 6, lane = t & 63;
  if (lane == 0){ sm[wid] = s; sm[8 + wid] = sq; }
  __syncthreads();
  s  = sm[0] + sm[1] + sm[2] + sm[3];
  sq = sm[8] + sm[9] + sm[10] + sm[11];
  float mu = s * (1.f / DIMV);
  float var = sq * (1.f / DIMV) - mu * mu;
  float r = rsqrtf(var + 1e-5f);
  float2 ww = ((const float2*)w0)[t];
  float2 bb = ((const float2*)b0)[t];
  float2 y;
  y.x = (v.x - mu) * r * ww.x + bb.x;
  y.y = (v.y - mu) * r * ww.y + bb.y;
  ushort2 xb; xb.x = f2bf(y.x); xb.y = f2bf(y.y);
  ((ushort2*)(x1 + row * DIMV))[t] = xb;
  float s2 = y.x + y.y, sq2 = y.x * y.x + y.y * y.y;
  wave_reduce2(s2, sq2);
  __syncthreads();
  if (lane == 0){ sm[wid] = s2; sm[8 + wid] = sq2; }
  __syncthreads();
  s2  = sm[0] + sm[1] + sm[2] + sm[3];
  sq2 = sm[8] + sm[9] + sm[10] + sm[11];
  float mu2 = s2 * (1.f / DIMV);
  float var2 = sq2 * (1.f / DIMV) - mu2 * mu2;
  float r2 = rsqrtf(var2 + 1e-5f);
  float2 w1v = ((const float2*)w1ln)[t];
  float2 b1v = ((const float2*)b1ln)[t];
  float hx = (y.x - mu2) * r2 * w1v.x + b1v.x;
  float hy = (y.y - mu2) * r2 * w1v.y + b1v.y;
  ushort2 hb; hb.x = f2bf(hx); hb.y = f2bf(hy);
  ((ushort2*)(h + row * DIMV))[t] = hb;
}

// ============================================================================
// 256x256 8-phase GEMM (learn_hip m201 template, plain HIP port, v2 schedule).
// BM=BN=256, BK=64, 512 threads = 8 waves (2M x 4N), per-wave 128x64 output.
// LDS = 128KB -> 1 block/CU. Both-sides chunk-XOR swizzle (bank-conflict 0,
// verified R7).
// v2 staging schedule (R7 fix): stage order matches NEXT-tile consumption
// order. Consumption: phase0 needs B-units 0-3 + A-units {0,2}; phases 2-3
// need A-units {1,3}. Stage per tile: p0: B0,B1 | p1: B2,B3 | p2: A0,A2 |
// p3: A1,A3. Waits: phase0 vmcnt(4) (drains exactly the 6 units needed now;
// leaves A1,A3 + 2 new B's in flight), end-of-phase1 vmcnt(4) (drains A1,A3
// before phases 2-3 read them). Every load gets >=2 full phases of latency
// cover; nothing waits on a load issued in the immediately preceding phase.
// SWAP=1 (w1): D row=af(fm), col=bf(quad*4+r) -> vectorized 8B stores.
// SWAP=0 (qkv): D col=bf(fm), row=af(quad*4+r) -> contiguous transposed-V
//              store into vt; Q cols pre-scaled by SC2.
// ============================================================================
template<int SWAP>
__global__ __launch_bounds__(512, 2) void gemm_8p(
    const __hip_bfloat16* __restrict__ A,
    const __hip_bfloat16* __restrict__ Bt,
    const float* __restrict__ bias,
    __hip_bfloat16* __restrict__ Cb,
    ushort* __restrict__ vt,
    int M, int N, int K, int gx, int dogelu)
{
  __shared__ __hip_bfloat16 As[2][256 * 64];
  __shared__ __hip_bfloat16 Bs[2][256 * 64];
  int tid = threadIdx.x;
  int l = tid & 63, w = tid >> 6;
  int wr = w >> 2, wc = w & 3;
  int fm = l & 15, quad = l >> 4;

  int bid = blockIdx.x;
  int xcd = bid & 7, idx = bid >> 3;
  int xl = idx % gx, yl = idx / gx;
  size_t bm = (size_t)(xcd * 8 + yl) * 256;
  size_t bn = (size_t)xl * 256;

  // staging map: unit j covers rows j*64 + (tid>>3), phys chunk tid&7,
  // source chunk pre-swizzled by row&7 (= (tid>>3)&7, invariant across j).
  int sr = tid >> 3;
  int sc = ((tid & 7) ^ (sr & 7)) * 8;
  const __hip_bfloat16* Ab0 = A + (bm + sr) * (size_t)K + sc;
  const __hip_bfloat16* Bb0 = Bt + (bn + sr) * (size_t)K + sc;
  int ldst = tid * 8;   // elems; + unit*4096

  int nk = K >> 6;

  // prologue: stage tile 0 into buf 0 in consumption order:
  // B0,B1,B2,B3, A0,A2, A1,A3  (FIFO order is what the vmcnt counting uses)
  #pragma unroll
  for (int j = 0; j < 4; j++)
    async_copy16(Bb0 + (size_t)j * 64 * K, &Bs[0][j * 4096 + ldst]);
  async_copy16(Ab0,                    &As[0][ldst]);
  async_copy16(Ab0 + (size_t)128 * K,  &As[0][2 * 4096 + ldst]);
  async_copy16(Ab0 + (size_t)64 * K,   &As[0][4096 + ldst]);
  async_copy16(Ab0 + (size_t)192 * K,  &As[0][3 * 4096 + ldst]);

  floatx4 acc[8][4] = {};

  int arow = wr * 128 + fm;   // + ri*16
  int brow = wc * 64 + fm;    // + ci*16
  int cx = fm & 7;            // read-side chunk XOR key (row&7)

  for (int t = 0; t < nk; ++t){
    int cur = t & 1, nxt = cur ^ 1;
    const __hip_bfloat16* Asrc = Ab0 + (size_t)(t + 1) * 64;
    const __hip_bfloat16* Bsrc = Bb0 + (size_t)(t + 1) * 64;
    const __hip_bfloat16* Ac = As[cur];
    const __hip_bfloat16* Bc = Bs[cur];
    short8 bf[4][2], af[2][2];

    // ---- phase 0: stage B0,B1(t+1); certify B0-3,A0,A2 of tile t ----
    if (t + 1 < nk){
      async_copy16(Bsrc, &Bs[nxt][ldst]);
      async_copy16(Bsrc + (size_t)64 * K, &Bs[nxt][4096 + ldst]);
      asm volatile("s_waitcnt vmcnt(4)\n\ts_barrier" ::: "memory");
    } else {
      asm volatile("s_waitcnt vmcnt(2)\n\ts_barrier" ::: "memory");
    }
    #pragma unroll
    for (int ci = 0; ci < 4; ci++)
      #pragma unroll
      for (int kb = 0; kb < 2; kb++)
        bf[ci][kb] = *(const short8*)&Bc[(brow + ci * 16) * 64 + ((kb * 4 + quad) ^ cx) * 8];
    #pragma unroll
    for (int i = 0; i < 2; i++)
      #pragma unroll
      for (int kb = 0; kb < 2; kb++)
        af[i][kb] = *(const short8*)&Ac[(arow + i * 16) * 64 + ((kb * 4 + quad) ^ cx) * 8];
    __builtin_amdgcn_s_setprio(1);
    #pragma unroll
    for (int i = 0; i < 2; i++)
      #pragma unroll
      for (int ci = 0; ci < 4; ci++)
        #pragma unroll
        for (int kb = 0; kb < 2; kb++){
          if (SWAP)
            acc[i][ci] = __builtin_amdgcn_mfma_f32_16x16x32_bf16(bf[ci][kb], af[i][kb], acc[i][ci], 0, 0, 0);
          else
            acc[i][ci] = __builtin_amdgcn_mfma_f32_16x16x32_bf16(af[i][kb], bf[ci][kb], acc[i][ci], 0, 0, 0);
        }
    __builtin_amdgcn_s_setprio(0);
    asm volatile("s_barrier" ::: "memory");

    // ---- phases 1..3 ----
    #pragma unroll
    for (int p = 1; p < 4; p++){
      #pragma unroll
      for (int i = 0; i < 2; i++)
        #pragma unroll
        for (int kb = 0; kb < 2; kb++)
          af[i][kb] = *(const short8*)&Ac[(arow + (p * 2 + i) * 16) * 64 + ((kb * 4 + quad) ^ cx) * 8];
      if (t + 1 < nk){
        if (p == 1){
          async_copy16(Bsrc + (size_t)128 * K, &Bs[nxt][2 * 4096 + ldst]);
          async_copy16(Bsrc + (size_t)192 * K, &Bs[nxt][3 * 4096 + ldst]);
        } else if (p == 2){
          async_copy16(Asrc, &As[nxt][ldst]);
          async_copy16(Asrc + (size_t)128 * K, &As[nxt][2 * 4096 + ldst]);
        } else {
          async_copy16(Asrc + (size_t)64 * K, &As[nxt][4096 + ldst]);
          async_copy16(Asrc + (size_t)192 * K, &As[nxt][3 * 4096 + ldst]);
        }
      }
      asm volatile("s_barrier" ::: "memory");
      __builtin_amdgcn_s_setprio(1);
      #pragma unroll
      for (int i = 0; i < 2; i++)
        #pragma unroll
        for (int ci = 0; ci < 4; ci++)
          #pragma unroll
          for (int kb = 0; kb < 2; kb++){
            if (SWAP)
              acc[p * 2 + i][ci] = __builtin_amdgcn_mfma_f32_16x16x32_bf16(bf[ci][kb], af[i][kb], acc[p * 2 + i][ci], 0, 0, 0);
            else
              acc[p * 2 + i][ci] = __builtin_amdgcn_mfma_f32_16x16x32_bf16(af[i][kb], bf[ci][kb], acc[p * 2 + i][ci], 0, 0, 0);
          }
      __builtin_amdgcn_s_setprio(0);
      if (p == 1){
        // certify A1,A3 of tile t before phases 2-3 read them
        if (t + 1 < nk)
          asm volatile("s_waitcnt vmcnt(4)\n\ts_barrier" ::: "memory");
        else
          asm volatile("s_waitcnt vmcnt(0)\n\ts_barrier" ::: "memory");
      } else {
        asm volatile("s_barrier" ::: "memory");
      }
    }
  }

  // ---- epilogue ----
  if (SWAP){
    // D: row = bm + wr*128 + ri*16 + fm ; col = bn + wc*64 + ci*16 + quad*4 + r
    #pragma unroll
    for (int ri = 0; ri < 8; ri++){
      size_t row = bm + wr * 128 + ri * 16 + fm;
      size_t rbase = row * (size_t)N + bn + wc * 64 + quad * 4;
      #pragma unroll
      for (int ci = 0; ci < 4; ci++){
        floatx4 v = acc[ri][ci];
        if (bias){
          floatx4 bv = *(const floatx4*)(bias + bn + wc * 64 + ci * 16 + quad * 4);
          #pragma unroll
          for (int r2 = 0; r2 < 4; r2++) v[r2] += bv[r2];
        }
        if (dogelu){
          #pragma unroll
          for (int r2 = 0; r2 < 4; r2++) v[r2] = fast_gelu(v[r2]);
        }
        ushortx4 ob;
        #pragma unroll
        for (int r2 = 0; r2 < 4; r2++) ob[r2] = f2bf(v[r2]);
        *(ushortx4*)((ushort*)Cb + rbase + ci * 16) = ob;
      }
    }
  } else {
    // D: col = bn + wc*64 + ci*16 + fm ; row = bm + wr*128 + ri*16 + quad*4 + r
    int b = (int)(bm >> 13), p = (int)((bm >> 10) & 7);
    int n0 = (int)(bm & 1023) + wr * 128 + quad * 4;   // + ri*16
    #pragma unroll
    for (int ci = 0; ci < 4; ci++){
      int col = (int)bn + wc * 64 + ci * 16 + fm;
      if (col >= 1024){
        int cc = col - 1024, hh = cc >> 6, dd = cc & 63;
        ushort* vdst = vt + ((size_t)((b * 8 + hh) * 8 + p)) * 65536 + (size_t)dd * 1024 + n0;
        #pragma unroll
        for (int ri = 0; ri < 8; ri++){
          ushortx4 v4;
          v4[0] = f2bf(acc[ri][ci][0]); v4[1] = f2bf(acc[ri][ci][1]);
          v4[2] = f2bf(acc[ri][ci][2]); v4[3] = f2bf(acc[ri][ci][3]);
          *(ushortx4*)(vdst + ri * 16) = v4;
        }
      } else {
        float scl = (col < 512) ? SC2 : 1.f;
        #pragma unroll
        for (int ri = 0; ri < 8; ri++){
          size_t rowb = bm + wr * 128 + ri * 16 + quad * 4;
          #pragma unroll
          for (int r2 = 0; r2 < 4; r2++)
            ((ushort*)Cb)[(rowb + r2) * (size_t)N + col] = f2bf(acc[ri][ci][r2] * scl);
        }
      }
    }
  }
}

// MFMA bf16 GEMM: BK=32, 128x128 tile, XCD-swizzled 1D grid (m97-class
// structure; kept for the N=512 GEMMs wo/w2 where 256^2 tiles under-fill the
// grid). 3-buffer LDS, 1 barrier/K-step, counted vmcnt.
template<int SWAP>
__global__ __launch_bounds__(256) void gemm_mfma(
    const __hip_bfloat16* __restrict__ A,
    const __hip_bfloat16* __restrict__ Bt,
    const float* __restrict__ bias,
    const __hip_bfloat16* __restrict__ Rb,
    float* __restrict__ Cf,
    __hip_bfloat16* __restrict__ Cb,
    ushort* __restrict__ vt,
    int M, int N, int K, int gx, int dogelu)
{
  __shared__ __hip_bfloat16 As[3][128 * 32];
  __shared__ __hip_bfloat16 Bs[3][128 * 32];
  int tid = threadIdx.x;
  int w = tid >> 6, l = tid & 63;

  int bid = blockIdx.x;
  int xcd = bid & 7, idx = bid >> 3;
  int xl = idx % gx, yl = idx / gx;
  size_t bm = (size_t)(xcd * 16 + yl) * 128;
  size_t bn = (size_t)xl * 128;
  int wm = (w & 1) * 64, wn = (w >> 1) * 64;

  int srow = w * 16 + (l >> 2);
  int gcs = ((l & 3) ^ (srow & 3)) * 8;
  const __hip_bfloat16* Ag0 = A + (bm + srow) * K + gcs;
  const __hip_bfloat16* Ag1 = A + (bm + 64 + srow) * K + gcs;
  const __hip_bfloat16* Bg0 = Bt + (bn + srow) * K + gcs;
  const __hip_bfloat16* Bg1 = Bt + (bn + 64 + srow) * K + gcs;
  int lo = srow * 32 + (l & 3) * 8;

  floatx4 acc[4][4] = {};
  int fm = l & 15;
  int quad = l >> 4;
  int cs = fm & 3;

  int nk = K >> 5;
  async_copy16(Ag0, &As[0][lo]);
  async_copy16(Ag1, &As[0][lo + 64 * 32]);
  async_copy16(Bg0, &Bs[0][lo]);
  async_copy16(Bg1, &Bs[0][lo + 64 * 32]);
  if (nk > 1){
    async_copy16(Ag0 + 32, &As[1][lo]);
    async_copy16(Ag1 + 32, &As[1][lo + 64 * 32]);
    async_copy16(Bg0 + 32, &Bs[1][lo]);
    async_copy16(Bg1 + 32, &Bs[1][lo + 64 * 32]);
  }

  int rb = 0;
  for (int it = 0; it < nk; ++it){
    if (it + 1 < nk)
      asm volatile("s_waitcnt vmcnt(4)\n\ts_barrier" ::: "memory");
    else
      asm volatile("s_waitcnt vmcnt(0)\n\ts_barrier" ::: "memory");
    if (it + 2 < nk){
      int wb = rb >= 1 ? rb - 1 : 2;
      int k0 = (it + 2) << 5;
      async_copy16(Ag0 + k0, &As[wb][lo]);
      async_copy16(Ag1 + k0, &As[wb][lo + 64 * 32]);
      async_copy16(Bg0 + k0, &Bs[wb][lo]);
      async_copy16(Bg1 + k0, &Bs[wb][lo + 64 * 32]);
    }
    const __hip_bfloat16* Ab = As[rb];
    const __hip_bfloat16* Bb = Bs[rb];
    short8 af[4], bf[4];
    #pragma unroll
    for (int i = 0; i < 4; i++){
      af[i] = *(const short8*)&Ab[(wm + i * 16 + fm) * 32 + ((quad ^ cs) * 8)];
      bf[i] = *(const short8*)&Bb[(wn + i * 16 + fm) * 32 + ((quad ^ cs) * 8)];
    }
    #pragma unroll
    for (int mi = 0; mi < 4; mi++)
      #pragma unroll
      for (int ni = 0; ni < 4; ni++){
        if (SWAP)
          acc[mi][ni] = __builtin_amdgcn_mfma_f32_16x16x32_bf16(bf[ni], af[mi], acc[mi][ni], 0, 0, 0);
        else
          acc[mi][ni] = __builtin_amdgcn_mfma_f32_16x16x32_bf16(af[mi], bf[ni], acc[mi][ni], 0, 0, 0);
      }
    rb = rb < 2 ? rb + 1 : 0;
  }

  int rq = quad * 4;
  if (SWAP){
    #pragma unroll
    for (int mi = 0; mi < 4; mi++){
      size_t row = bm + wm + mi * 16 + fm;
      size_t rbase = row * (size_t)N + bn + wn + rq;
      #pragma unroll
      for (int ni = 0; ni < 4; ni++){
        size_t idx2 = rbase + ni * 16;
        floatx4 v = acc[mi][ni];
        if (bias){
          floatx4 bv = *(const floatx4*)(bias + bn + wn + ni * 16 + rq);
          #pragma unroll
          for (int r2 = 0; r2 < 4; r2++) v[r2] += bv[r2];
        }
        if (dogelu){
          #pragma unroll
          for (int r2 = 0; r2 < 4; r2++) v[r2] = fast_gelu(v[r2]);
        }
        if (Rb){
          ushortx4 rbv = *(const ushortx4*)((const ushort*)Rb + idx2);
          #pragma unroll
          for (int r2 = 0; r2 < 4; r2++) v[r2] += bf2f(rbv[r2]);
        }
        if (Cb){
          ushortx4 ob;
          #pragma unroll
          for (int r2 = 0; r2 < 4; r2++) ob[r2] = f2bf(v[r2]);
          *(ushortx4*)((ushort*)Cb + idx2) = ob;
        } else {
          *(floatx4*)(Cf + idx2) = v;
        }
      }
    }
  } else {
    #pragma unroll
    for (int ni = 0; ni < 4; ni++){
      size_t col = bn + wn + ni * 16 + fm;
      float bv = bias ? bias[col] : 0.f;
      #pragma unroll
      for (int mi = 0; mi < 4; mi++){
        #pragma unroll
        for (int r2 = 0; r2 < 4; r2++){
          size_t row = bm + wm + mi * 16 + rq + r2;
          float v = acc[mi][ni][r2] + bv;
          if (dogelu) v = fast_gelu(v);
          size_t idx2 = row * N + col;
          if (Rb) v += bf2f(((const ushort*)Rb)[idx2]);
          Cf[idx2] = v;
        }
      }
    }
  }
}

// MFMA flash attention (round-6 verified). Q pre-scaled by SC2.
__global__ __launch_bounds__(256, 4) void attn_mfma(const __hip_bfloat16* __restrict__ qkvp,
                                                    const ushort* __restrict__ vt,
                                                    __hip_bfloat16* __restrict__ outp){
  __shared__ ushort Ks[2][64 * 64];
  __shared__ ushort Vs[2][64 * 64];
  __shared__ ushort Ps[4][32 * 32];
  int tid = threadIdx.x;
  int w = tid >> 6, l = tid & 63;
  int r15 = l & 15, quad = l >> 4, fq = quad * 8;
  int slice = blockIdx.x & 127;
  int qc = blockIdx.x >> 7;
  int b = slice >> 6, hh = (slice >> 3) & 7, p = slice & 7;
  const ushort* base = (const ushort*)qkvp + (size_t)(b * PPV + p) * NSEQ * QKVW;
  const ushort* kb = base + 512 + hh * DHEAD;
  const ushort* vb = vt + (size_t)slice * 65536;

  int s0 = w * 64 + l, s1 = 256 + w * 64 + l;
  int row0 = s0 >> 3, row1 = s1 >> 3;
  int gc0 = (s0 & 7) ^ (row0 & 7), gc1 = (s1 & 7) ^ (row1 & 7);
  const ushort* kp0 = kb + (size_t)row0 * QKVW + gc0 * 8;
  const ushort* kp1 = kb + (size_t)row1 * QKVW + gc1 * 8;
  const ushort* vp0 = vb + (size_t)row0 * 1024 + gc0 * 8;
  const ushort* vp1 = vb + (size_t)row1 * 1024 + gc1 * 8;

  async_copy16(kp0, &Ks[0][s0 * 8]);
  async_copy16(kp1, &Ks[0][s1 * 8]);
  async_copy16(vp0, &Vs[0][s0 * 8]);
  async_copy16(vp1, &Vs[0][s1 * 8]);

  int q0 = qc * 128 + w * 32;
  short8 qf[2][2];
  #pragma unroll
  for (int mi = 0; mi < 2; mi++)
    #pragma unroll
    for (int kk = 0; kk < 2; kk++)
      qf[mi][kk] = *(const short8*)(base + (size_t)(q0 + mi * 16 + r15) * QKVW + hh * DHEAD + kk * 32 + fq);

  floatx4 o[2][4] = {};
  floatx4 lacc[2] = {};
  short8 ones;
  #pragma unroll
  for (int j = 0; j < 8; j++) ones[j] = (short)0x3F80;

  int sw = r15 & 7;
  int swp = (r15 & 3) << 3;
  ushort* PsW = Ps[w];

  for (int it = 0; it < NSEQ / 64; ++it){
    int cur = it & 1;
    asm volatile("s_waitcnt vmcnt(0)\n\ts_barrier" ::: "memory");
    if (it + 1 < NSEQ / 64){
      int nxt = cur ^ 1;
      kp0 += 64 * QKVW; kp1 += 64 * QKVW; vp0 += 64; vp1 += 64;
      async_copy16(kp0, &Ks[nxt][s0 * 8]);
      async_copy16(kp1, &Ks[nxt][s1 * 8]);
      async_copy16(vp0, &Vs[nxt][s0 * 8]);
      async_copy16(vp1, &Vs[nxt][s1 * 8]);
    }
    const ushort* Kb = Ks[cur];
    const ushort* Vb = Vs[cur];

    short8 pf[2][2];
    #pragma unroll
    for (int kk = 0; kk < 2; kk++){
      #pragma unroll
      for (int nn = 0; nn < 2; nn++){
        int ni = kk * 2 + nn;
        int rb2 = (ni * 16 + r15) * 64;
        short8 kf0 = *(const short8*)&Kb[rb2 + (quad ^ sw) * 8];
        short8 kf1 = *(const short8*)&Kb[rb2 + ((4 + quad) ^ sw) * 8];
        floatx4 sA = {}, sB = {};
        sA = __builtin_amdgcn_mfma_f32_16x16x32_bf16(kf0, qf[0][0], sA, 0, 0, 0);
        sA = __builtin_amdgcn_mfma_f32_16x16x32_bf16(kf1, qf[0][1], sA, 0, 0, 0);
        sB = __builtin_amdgcn_mfma_f32_16x16x32_bf16(kf0, qf[1][0], sB, 0, 0, 0);
        sB = __builtin_amdgcn_mfma_f32_16x16x32_bf16(kf1, qf[1][1], sB, 0, 0, 0);
        int wc = (nn * 16 + quad * 4) ^ swp;
        union { float f; uint u; } e0, e1, e2, e3;
        uint2 pk;
        e0.f = exp2f(sA[0]); e1.f = exp2f(sA[1]);
        e2.f = exp2f(sA[2]); e3.f = exp2f(sA[3]);
        pk.x = __builtin_amdgcn_perm(e1.u, e0.u, 0x07060302u);
        pk.y = __builtin_amdgcn_perm(e3.u, e2.u, 0x07060302u);
        *(uint2*)&PsW[r15 * 32 + wc] = pk;
        e0.f = exp2f(sB[0]); e1.f = exp2f(sB[1]);
        e2.f = exp2f(sB[2]); e3.f = exp2f(sB[3]);
        pk.x = __builtin_amdgcn_perm(e1.u, e0.u, 0x07060302u);
        pk.y = __builtin_amdgcn_perm(e3.u, e2.u, 0x07060302u);
        *(uint2*)&PsW[(16 + r15) * 32 + wc] = pk;
      }
      asm volatile("s_waitcnt lgkmcnt(0)" ::: "memory");
      pf[0][kk] = *(const short8*)&PsW[r15 * 32 + (fq ^ swp)];
      pf[1][kk] = *(const short8*)&PsW[(16 + r15) * 32 + (fq ^ swp)];
      asm volatile("s_waitcnt lgkmcnt(0)" ::: "memory");
    }

    #pragma unroll
    for (int mi = 0; mi < 2; mi++)
      #pragma unroll
      for (int kk = 0; kk < 2; kk++)
        lacc[mi] = __builtin_amdgcn_mfma_f32_16x16x32_bf16(ones, pf[mi][kk], lacc[mi], 0, 0, 0);

    #pragma unroll
    for (int dj = 0; dj < 4; dj++){
      int d = dj * 16 + r15;
      short8 vf0 = *(const short8*)&Vb[d * 64 + ((quad) ^ sw) * 8];
      short8 vf1 = *(const short8*)&Vb[d * 64 + ((4 + quad) ^ sw) * 8];
      #pragma unroll
      for (int mi = 0; mi < 2; mi++){
        o[mi][dj] = __builtin_amdgcn_mfma_f32_16x16x32_bf16(vf0, pf[mi][0], o[mi][dj], 0, 0, 0);
        o[mi][dj] = __builtin_amdgcn_mfma_f32_16x16x32_bf16(vf1, pf[mi][1], o[mi][dj], 0, 0, 0);
      }
    }
  }

  #pragma unroll
  for (int mi = 0; mi < 2; mi++){
    float inv = __builtin_amdgcn_rcpf(lacc[mi][0]);
    size_t n = q0 + mi * 16 + r15;
    ushort* orow = (ushort*)outp + ((size_t)((b * HEADSV + hh) * NSEQ + n)) * DIMV + p * DHEAD + quad * 4;
    #pragma unroll
    for (int dj = 0; dj < 4; dj++){
      ushortx4 ov;
      #pragma unroll
      for (int r = 0; r < 4; r++) ov[r] = f2bf(o[mi][dj][r] * inv);
      *(ushortx4*)(orow + dj * 16) = ov;
    }
  }
}

extern "C" void kernel_launch(void* const* d_in, const int* in_sizes, int n_in,
                              void* d_out, int out_size, void* d_ws, size_t ws_size,
                              hipStream_t stream){
  (void)in_sizes; (void)n_in; (void)out_size; (void)ws_size;
  const float* x    = (const float*)d_in[0];
  const float* lw0  = (const float*)d_in[1];
  const float* lb0  = (const float*)d_in[2];
  const float* lw1  = (const float*)d_in[3];
  const float* lb1  = (const float*)d_in[4];
  const float* wqkv = (const float*)d_in[5];
  const float* wo   = (const float*)d_in[6];
  const float* bo   = (const float*)d_in[7];
  const float* w1   = (const float*)d_in[8];
  const float* b1   = (const float*)d_in[9];
  const float* w2   = (const float*)d_in[10];
  const float* b2   = (const float*)d_in[11];
  float* out = (float*)d_out;
  char* ws = (char*)d_ws;
  const size_t MB = 1024 * 1024;

  __hip_bfloat16* x1b  = (__hip_bfloat16*)(ws);
  ushort* vtbuf        = (ushort*)(ws + 32 * MB);
  __hip_bfloat16* x2b  = (__hip_bfloat16*)(ws + 64 * MB);
  __hip_bfloat16* wqkvT= (__hip_bfloat16*)(ws + 80 * MB);
  __hip_bfloat16* woT  = (__hip_bfloat16*)(ws + 82 * MB);
  __hip_bfloat16* w1T  = (__hip_bfloat16*)(ws + 83 * MB);
  __hip_bfloat16* w2T  = (__hip_bfloat16*)(ws + 85 * MB);
  __hip_bfloat16* hB   = (__hip_bfloat16*)(ws + 88 * MB);
  __hip_bfloat16* attnB= hB;
  __hip_bfloat16* qkvB = (__hip_bfloat16*)(ws + 104 * MB);
  __hip_bfloat16* tB   = (__hip_bfloat16*)(ws + 88 * MB);

  // 1) fused prep: LN (16384 blocks) + 4 weight transposes (3072 blocks)
  prep_kernel<<<NTOK + 3072, 256, 0, stream>>>(
      x, lw0, lb0, lw1, lb1, x1b, hB,
      wqkv, wqkvT, wo, woT, w1, w1T, w2, w2T);

  // 2) qkv = h @ w_qkv -> bf16 (Q scaled by SC2, K) + transposed V into vtbuf
  //    8-phase 256^2 kernel: grid (16384/256)x(1536/256) = 64x6 = 384
  gemm_8p<0><<<384, 512, 0, stream>>>(
      hB, wqkvT, nullptr, qkvB, vtbuf, NTOK, QKVW, DIMV, 6, 0);

  // 3) attention
  attn_mfma<<<1024, 256, 0, stream>>>(qkvB, vtbuf, attnB);

  // 4) x2b = attn @ w_o + b_o + x1b -> bf16 (N=512: keep 128^2 kernel)
  gemm_mfma<1><<<(DIMV / 128) * 128, 256, 0, stream>>>(
      attnB, woT, bo, x1b, nullptr, x2b, nullptr,
      NTOK, DIMV, DIMV, DIMV / 128, 0);

  // 5) t = gelu_fast(x2b @ w1 + b1) -> bf16
  //    8-phase 256^2 kernel: grid 64x8 = 512
  gemm_8p<1><<<512, 512, 0, stream>>>(
      x2b, w1T, b1, tB, nullptr, NTOK, HIDV, DIMV, 8, 1);

  // 6) out = t @ w2 + b2 + x2b -> fp32 (N=512: keep 128^2 kernel)
  gemm_mfma<1><<<(DIMV / 128) * 128, 256, 0, stream>>>(
      tB, w2T, b2, x2b, out, nullptr, nullptr,
      NTOK, DIMV, HIDV, DIMV / 128, 0);
}

// Round 9
// 352.954 us; speedup vs baseline: 1.0404x; 1.0404x over previous
//
#include <hip/hip_runtime.h>
#include <hip/hip_bf16.h>
#include <math.h>

#define DIMV 512
#define NTOK 16384   // B*P*N = 2*8*1024
#define NSEQ 1024
#define HEADSV 8
#define PPV 8
#define DHEAD 64
#define QKVW 1536
#define HIDV 2048
#define SC2 0.18033688011112042f   // 0.125 * log2(e)

typedef unsigned short ushort;
typedef unsigned int uint;
typedef __attribute__((ext_vector_type(8))) short short8;
typedef __attribute__((ext_vector_type(8))) unsigned short ushort8;
typedef __attribute__((ext_vector_type(4))) unsigned short ushortx4;
typedef __attribute__((ext_vector_type(4))) float floatx4;

__device__ __forceinline__ float bf2f(ushort u){
  union { unsigned int i; float f; } c; c.i = ((unsigned int)u) << 16; return c.f;
}
// fast RNE f32->bf16 (finite values; no NaN branch): 3 VALU
__device__ __forceinline__ ushort f2bf(float f){
  union { float f; unsigned int i; } c; c.f = f;
  unsigned int u = c.i + 0x7fffu + ((c.i >> 16) & 1u);
  return (ushort)(u >> 16);
}
__device__ __forceinline__ void async_copy16(const void* gptr, void* lptr){
  __builtin_amdgcn_global_load_lds((const __attribute__((address_space(1))) void*)gptr,
                                   (__attribute__((address_space(3))) void*)lptr, 16, 0, 0);
}
// tanh-form GELU via one v_exp_f32: x * sigmoid(1.5957691x + 0.0713548x^3)
__device__ __forceinline__ float fast_gelu(float x){
  float u = x * (2.3022084f + 0.1029435f * x * x);   // (2u)*log2(e)
  return x * __builtin_amdgcn_rcpf(1.f + exp2f(-u));
}

__device__ __forceinline__ void wave_reduce2(float& a, float& b){
  #pragma unroll
  for (int off = 32; off > 0; off >>= 1){
    a += __shfl_down(a, off, 64);
    b += __shfl_down(b, off, 64);
  }
}

// ---- fused prep kernel: LN (blocks [0,16384)) + 4 weight transposes ----
__device__ __forceinline__ void wtrans_body(const float* __restrict__ W,
    __hip_bfloat16* __restrict__ Wt, int K, int N, int bx, int by, int t,
    float* tile /* 32*33 */){
  int bn = bx * 32, bk = by * 32;
  int tx = t & 31, ty = t >> 5;
  #pragma unroll
  for (int i = 0; i < 32; i += 8)
    tile[(ty + i) * 33 + tx] = W[(size_t)(bk + ty + i) * N + bn + tx];
  __syncthreads();
  #pragma unroll
  for (int i = 0; i < 32; i += 8)
    Wt[(size_t)(bn + ty + i) * K + bk + tx] = __float2bfloat16(tile[tx * 33 + ty + i]);
}

__global__ __launch_bounds__(256) void prep_kernel(const float* __restrict__ x,
    const float* __restrict__ w0, const float* __restrict__ b0,
    const float* __restrict__ w1ln, const float* __restrict__ b1ln,
    __hip_bfloat16* __restrict__ x1, __hip_bfloat16* __restrict__ h,
    const float* __restrict__ wqkv, __hip_bfloat16* __restrict__ wqkvT,
    const float* __restrict__ wo,   __hip_bfloat16* __restrict__ woT,
    const float* __restrict__ w1,   __hip_bfloat16* __restrict__ w1T,
    const float* __restrict__ w2,   __hip_bfloat16* __restrict__ w2T){
  __shared__ float smem[32 * 33];
  int bid = blockIdx.x;
  int t = threadIdx.x;
  if (bid >= NTOK){
    int r = bid - NTOK;
    if (r < 768)        wtrans_body(wqkv, wqkvT, 512, 1536, r % 48, r / 48, t, smem);
    else if (r < 1024){ r -= 768;  wtrans_body(wo, woT, 512, 512,  r % 16, r / 16, t, smem); }
    else if (r < 2048){ r -= 1024; wtrans_body(w1, w1T, 512, 2048, r % 64, r / 64, t, smem); }
    else             { r -= 2048; wtrans_body(w2, w2T, 2048, 512, r % 16, r / 16, t, smem); }
    return;
  }
  // ---- double LN ----
  float* sm = smem;
  size_t row = bid;
  const float2* xr = (const float2*)(x + row * DIMV);
  float2 v = xr[t];
  float s = v.x + v.y;
  float sq = v.x * v.x + v.y * v.y;
  wave_reduce2(s, sq);
  int wid = t >> 6, lane = t & 63;
  if (lane == 0){ sm[wid] = s; sm[8 + wid] = sq; }
  __syncthreads();
  s  = sm[0] + sm[1] + sm[2] + sm[3];
  sq = sm[8] + sm[9] + sm[10] + sm[11];
  float mu = s * (1.f / DIMV);
  float var = sq * (1.f / DIMV) - mu * mu;
  float r = rsqrtf(var + 1e-5f);
  float2 ww = ((const float2*)w0)[t];
  float2 bb = ((const float2*)b0)[t];
  float2 y;
  y.x = (v.x - mu) * r * ww.x + bb.x;
  y.y = (v.y - mu) * r * ww.y + bb.y;
  ushort2 xb; xb.x = f2bf(y.x); xb.y = f2bf(y.y);
  ((ushort2*)(x1 + row * DIMV))[t] = xb;
  float s2 = y.x + y.y, sq2 = y.x * y.x + y.y * y.y;
  wave_reduce2(s2, sq2);
  __syncthreads();
  if (lane == 0){ sm[wid] = s2; sm[8 + wid] = sq2; }
  __syncthreads();
  s2  = sm[0] + sm[1] + sm[2] + sm[3];
  sq2 = sm[8] + sm[9] + sm[10] + sm[11];
  float mu2 = s2 * (1.f / DIMV);
  float var2 = sq2 * (1.f / DIMV) - mu2 * mu2;
  float r2 = rsqrtf(var2 + 1e-5f);
  float2 w1v = ((const float2*)w1ln)[t];
  float2 b1v = ((const float2*)b1ln)[t];
  float hx = (y.x - mu2) * r2 * w1v.x + b1v.x;
  float hy = (y.y - mu2) * r2 * w1v.y + b1v.y;
  ushort2 hb; hb.x = f2bf(hx); hb.y = f2bf(hy);
  ((ushort2*)(h + row * DIMV))[t] = hb;
}

// ============================================================================
// 256x256 GEMM, v3 schedule. BM=BN=256, BK=64, 512 threads = 8 waves (2Mx4N),
// per-wave 128x64 output. LDS = 128KB -> 1 block/CU. Chunk-XOR swizzle
// (bank-conflict 0, verified R7).
// v3 (R8 post-mortem): ONE vmcnt(0)+barrier per K-tile. All 8 stage units for
// tile t+1 are issued right after the tile-t barrier (A first: slow L3/HBM
// activations get max cover; B last: L2-hot weights) -> full-tile (~2500cy)
// latency cover, no counted-vmcnt choreography to get wrong. Correctness:
// within a tile all waves only READ buf[cur]; staging writes buf[nxt];
// every wave's ds_reads of tile t-1 are lgkm-drained before its t-1 MFMAs
// issued, hence before it reaches tile t's barrier -> overwrite is race-free.
// One plain mid-tile barrier bounds the compiler's scheduling scope (register
// pressure), not correctness. No setprio (no role-split). Waves free-run and
// overlap on the MFMA/LDS pipes instead of convoying through 8 barriers/tile.
// SWAP=1 (w1): D row=af(fm), col=bf(quad*4+r) -> vectorized 8B stores.
// SWAP=0 (qkv): D col=bf(fm), row=af(quad*4+r) -> contiguous transposed-V
//              store into vt; Q cols pre-scaled by SC2.
// ============================================================================
template<int SWAP>
__global__ __launch_bounds__(512, 2) void gemm_8p(
    const __hip_bfloat16* __restrict__ A,
    const __hip_bfloat16* __restrict__ Bt,
    const float* __restrict__ bias,
    __hip_bfloat16* __restrict__ Cb,
    ushort* __restrict__ vt,
    int M, int N, int K, int gx, int dogelu)
{
  __shared__ __hip_bfloat16 As[2][256 * 64];
  __shared__ __hip_bfloat16 Bs[2][256 * 64];
  int tid = threadIdx.x;
  int l = tid & 63, w = tid >> 6;
  int wr = w >> 2, wc = w & 3;
  int fm = l & 15, quad = l >> 4;

  int bid = blockIdx.x;
  int xcd = bid & 7, idx = bid >> 3;
  int xl = idx % gx, yl = idx / gx;
  size_t bm = (size_t)(xcd * 8 + yl) * 256;
  size_t bn = (size_t)xl * 256;

  // staging map: unit j covers rows j*64 + (tid>>3), phys chunk tid&7,
  // source chunk pre-swizzled by row&7 (= (tid>>3)&7, invariant across j).
  int sr = tid >> 3;
  int sc = ((tid & 7) ^ (sr & 7)) * 8;
  const __hip_bfloat16* Ab0 = A + (bm + sr) * (size_t)K + sc;
  const __hip_bfloat16* Bb0 = Bt + (bn + sr) * (size_t)K + sc;
  int ldst = tid * 8;   // elems; + unit*4096

  int nk = K >> 6;

  // prologue: stage tile 0 into buf 0 (A first — slow loads get max cover)
  #pragma unroll
  for (int j = 0; j < 4; j++)
    async_copy16(Ab0 + (size_t)j * 64 * K, &As[0][j * 4096 + ldst]);
  #pragma unroll
  for (int j = 0; j < 4; j++)
    async_copy16(Bb0 + (size_t)j * 64 * K, &Bs[0][j * 4096 + ldst]);

  floatx4 acc[8][4] = {};

  int arow = wr * 128 + fm;   // + ri*16
  int brow = wc * 64 + fm;    // + ci*16
  int cx = fm & 7;            // read-side chunk XOR key (row&7)

  for (int t = 0; t < nk; ++t){
    int cur = t & 1, nxt = cur ^ 1;
    // certify tile t (only its 8 loads are outstanding; issued a full tile ago)
    asm volatile("s_waitcnt vmcnt(0)\n\ts_barrier" ::: "memory");
    if (t + 1 < nk){
      const __hip_bfloat16* Asrc = Ab0 + (size_t)(t + 1) * 64;
      const __hip_bfloat16* Bsrc = Bb0 + (size_t)(t + 1) * 64;
      #pragma unroll
      for (int j = 0; j < 4; j++)
        async_copy16(Asrc + (size_t)j * 64 * K, &As[nxt][j * 4096 + ldst]);
      #pragma unroll
      for (int j = 0; j < 4; j++)
        async_copy16(Bsrc + (size_t)j * 64 * K, &Bs[nxt][j * 4096 + ldst]);
    }
    const __hip_bfloat16* Ac = As[cur];
    const __hip_bfloat16* Bc = Bs[cur];
    short8 bf[4][2];
    #pragma unroll
    for (int ci = 0; ci < 4; ci++)
      #pragma unroll
      for (int kb = 0; kb < 2; kb++)
        bf[ci][kb] = *(const short8*)&Bc[(brow + ci * 16) * 64 + ((kb * 4 + quad) ^ cx) * 8];
    #pragma unroll
    for (int p = 0; p < 4; p++){
      short8 af[2][2];
      #pragma unroll
      for (int i = 0; i < 2; i++)
        #pragma unroll
        for (int kb = 0; kb < 2; kb++)
          af[i][kb] = *(const short8*)&Ac[(arow + (p * 2 + i) * 16) * 64 + ((kb * 4 + quad) ^ cx) * 8];
      #pragma unroll
      for (int i = 0; i < 2; i++)
        #pragma unroll
        for (int ci = 0; ci < 4; ci++)
          #pragma unroll
          for (int kb = 0; kb < 2; kb++){
            if (SWAP)
              acc[p * 2 + i][ci] = __builtin_amdgcn_mfma_f32_16x16x32_bf16(bf[ci][kb], af[i][kb], acc[p * 2 + i][ci], 0, 0, 0);
            else
              acc[p * 2 + i][ci] = __builtin_amdgcn_mfma_f32_16x16x32_bf16(af[i][kb], bf[ci][kb], acc[p * 2 + i][ci], 0, 0, 0);
          }
      if (p == 1)
        asm volatile("s_barrier" ::: "memory");   // scheduling fence only
    }
  }

  // ---- epilogue ----
  if (SWAP){
    // D: row = bm + wr*128 + ri*16 + fm ; col = bn + wc*64 + ci*16 + quad*4 + r
    #pragma unroll
    for (int ri = 0; ri < 8; ri++){
      size_t row = bm + wr * 128 + ri * 16 + fm;
      size_t rbase = row * (size_t)N + bn + wc * 64 + quad * 4;
      #pragma unroll
      for (int ci = 0; ci < 4; ci++){
        floatx4 v = acc[ri][ci];
        if (bias){
          floatx4 bv = *(const floatx4*)(bias + bn + wc * 64 + ci * 16 + quad * 4);
          #pragma unroll
          for (int r2 = 0; r2 < 4; r2++) v[r2] += bv[r2];
        }
        if (dogelu){
          #pragma unroll
          for (int r2 = 0; r2 < 4; r2++) v[r2] = fast_gelu(v[r2]);
        }
        ushortx4 ob;
        #pragma unroll
        for (int r2 = 0; r2 < 4; r2++) ob[r2] = f2bf(v[r2]);
        *(ushortx4*)((ushort*)Cb + rbase + ci * 16) = ob;
      }
    }
  } else {
    // D: col = bn + wc*64 + ci*16 + fm ; row = bm + wr*128 + ri*16 + quad*4 + r
    int b = (int)(bm >> 13), p = (int)((bm >> 10) & 7);
    int n0 = (int)(bm & 1023) + wr * 128 + quad * 4;   // + ri*16
    #pragma unroll
    for (int ci = 0; ci < 4; ci++){
      int col = (int)bn + wc * 64 + ci * 16 + fm;
      if (col >= 1024){
        int cc = col - 1024, hh = cc >> 6, dd = cc & 63;
        ushort* vdst = vt + ((size_t)((b * 8 + hh) * 8 + p)) * 65536 + (size_t)dd * 1024 + n0;
        #pragma unroll
        for (int ri = 0; ri < 8; ri++){
          ushortx4 v4;
          v4[0] = f2bf(acc[ri][ci][0]); v4[1] = f2bf(acc[ri][ci][1]);
          v4[2] = f2bf(acc[ri][ci][2]); v4[3] = f2bf(acc[ri][ci][3]);
          *(ushortx4*)(vdst + ri * 16) = v4;
        }
      } else {
        float scl = (col < 512) ? SC2 : 1.f;
        #pragma unroll
        for (int ri = 0; ri < 8; ri++){
          size_t rowb = bm + wr * 128 + ri * 16 + quad * 4;
          #pragma unroll
          for (int r2 = 0; r2 < 4; r2++)
            ((ushort*)Cb)[(rowb + r2) * (size_t)N + col] = f2bf(acc[ri][ci][r2] * scl);
        }
      }
    }
  }
}

// MFMA bf16 GEMM: BK=32, 128x128 tile, XCD-swizzled 1D grid (m97-class
// structure; kept for the N=512 GEMMs wo/w2 where 256^2 tiles under-fill the
// grid). 3-buffer LDS, 1 barrier/K-step, counted vmcnt.
template<int SWAP>
__global__ __launch_bounds__(256) void gemm_mfma(
    const __hip_bfloat16* __restrict__ A,
    const __hip_bfloat16* __restrict__ Bt,
    const float* __restrict__ bias,
    const __hip_bfloat16* __restrict__ Rb,
    float* __restrict__ Cf,
    __hip_bfloat16* __restrict__ Cb,
    ushort* __restrict__ vt,
    int M, int N, int K, int gx, int dogelu)
{
  __shared__ __hip_bfloat16 As[3][128 * 32];
  __shared__ __hip_bfloat16 Bs[3][128 * 32];
  int tid = threadIdx.x;
  int w = tid >> 6, l = tid & 63;

  int bid = blockIdx.x;
  int xcd = bid & 7, idx = bid >> 3;
  int xl = idx % gx, yl = idx / gx;
  size_t bm = (size_t)(xcd * 16 + yl) * 128;
  size_t bn = (size_t)xl * 128;
  int wm = (w & 1) * 64, wn = (w >> 1) * 64;

  int srow = w * 16 + (l >> 2);
  int gcs = ((l & 3) ^ (srow & 3)) * 8;
  const __hip_bfloat16* Ag0 = A + (bm + srow) * K + gcs;
  const __hip_bfloat16* Ag1 = A + (bm + 64 + srow) * K + gcs;
  const __hip_bfloat16* Bg0 = Bt + (bn + srow) * K + gcs;
  const __hip_bfloat16* Bg1 = Bt + (bn + 64 + srow) * K + gcs;
  int lo = srow * 32 + (l & 3) * 8;

  floatx4 acc[4][4] = {};
  int fm = l & 15;
  int quad = l >> 4;
  int cs = fm & 3;

  int nk = K >> 5;
  async_copy16(Ag0, &As[0][lo]);
  async_copy16(Ag1, &As[0][lo + 64 * 32]);
  async_copy16(Bg0, &Bs[0][lo]);
  async_copy16(Bg1, &Bs[0][lo + 64 * 32]);
  if (nk > 1){
    async_copy16(Ag0 + 32, &As[1][lo]);
    async_copy16(Ag1 + 32, &As[1][lo + 64 * 32]);
    async_copy16(Bg0 + 32, &Bs[1][lo]);
    async_copy16(Bg1 + 32, &Bs[1][lo + 64 * 32]);
  }

  int rb = 0;
  for (int it = 0; it < nk; ++it){
    if (it + 1 < nk)
      asm volatile("s_waitcnt vmcnt(4)\n\ts_barrier" ::: "memory");
    else
      asm volatile("s_waitcnt vmcnt(0)\n\ts_barrier" ::: "memory");
    if (it + 2 < nk){
      int wb = rb >= 1 ? rb - 1 : 2;
      int k0 = (it + 2) << 5;
      async_copy16(Ag0 + k0, &As[wb][lo]);
      async_copy16(Ag1 + k0, &As[wb][lo + 64 * 32]);
      async_copy16(Bg0 + k0, &Bs[wb][lo]);
      async_copy16(Bg1 + k0, &Bs[wb][lo + 64 * 32]);
    }
    const __hip_bfloat16* Ab = As[rb];
    const __hip_bfloat16* Bb = Bs[rb];
    short8 af[4], bf[4];
    #pragma unroll
    for (int i = 0; i < 4; i++){
      af[i] = *(const short8*)&Ab[(wm + i * 16 + fm) * 32 + ((quad ^ cs) * 8)];
      bf[i] = *(const short8*)&Bb[(wn + i * 16 + fm) * 32 + ((quad ^ cs) * 8)];
    }
    #pragma unroll
    for (int mi = 0; mi < 4; mi++)
      #pragma unroll
      for (int ni = 0; ni < 4; ni++){
        if (SWAP)
          acc[mi][ni] = __builtin_amdgcn_mfma_f32_16x16x32_bf16(bf[ni], af[mi], acc[mi][ni], 0, 0, 0);
        else
          acc[mi][ni] = __builtin_amdgcn_mfma_f32_16x16x32_bf16(af[mi], bf[ni], acc[mi][ni], 0, 0, 0);
      }
    rb = rb < 2 ? rb + 1 : 0;
  }

  int rq = quad * 4;
  if (SWAP){
    #pragma unroll
    for (int mi = 0; mi < 4; mi++){
      size_t row = bm + wm + mi * 16 + fm;
      size_t rbase = row * (size_t)N + bn + wn + rq;
      #pragma unroll
      for (int ni = 0; ni < 4; ni++){
        size_t idx2 = rbase + ni * 16;
        floatx4 v = acc[mi][ni];
        if (bias){
          floatx4 bv = *(const floatx4*)(bias + bn + wn + ni * 16 + rq);
          #pragma unroll
          for (int r2 = 0; r2 < 4; r2++) v[r2] += bv[r2];
        }
        if (dogelu){
          #pragma unroll
          for (int r2 = 0; r2 < 4; r2++) v[r2] = fast_gelu(v[r2]);
        }
        if (Rb){
          ushortx4 rbv = *(const ushortx4*)((const ushort*)Rb + idx2);
          #pragma unroll
          for (int r2 = 0; r2 < 4; r2++) v[r2] += bf2f(rbv[r2]);
        }
        if (Cb){
          ushortx4 ob;
          #pragma unroll
          for (int r2 = 0; r2 < 4; r2++) ob[r2] = f2bf(v[r2]);
          *(ushortx4*)((ushort*)Cb + idx2) = ob;
        } else {
          *(floatx4*)(Cf + idx2) = v;
        }
      }
    }
  } else {
    #pragma unroll
    for (int ni = 0; ni < 4; ni++){
      size_t col = bn + wn + ni * 16 + fm;
      float bv = bias ? bias[col] : 0.f;
      #pragma unroll
      for (int mi = 0; mi < 4; mi++){
        #pragma unroll
        for (int r2 = 0; r2 < 4; r2++){
          size_t row = bm + wm + mi * 16 + rq + r2;
          float v = acc[mi][ni][r2] + bv;
          if (dogelu) v = fast_gelu(v);
          size_t idx2 = row * N + col;
          if (Rb) v += bf2f(((const ushort*)Rb)[idx2]);
          Cf[idx2] = v;
        }
      }
    }
  }
}

// MFMA flash attention (round-6 verified). Q pre-scaled by SC2.
__global__ __launch_bounds__(256, 4) void attn_mfma(const __hip_bfloat16* __restrict__ qkvp,
                                                    const ushort* __restrict__ vt,
                                                    __hip_bfloat16* __restrict__ outp){
  __shared__ ushort Ks[2][64 * 64];
  __shared__ ushort Vs[2][64 * 64];
  __shared__ ushort Ps[4][32 * 32];
  int tid = threadIdx.x;
  int w = tid >> 6, l = tid & 63;
  int r15 = l & 15, quad = l >> 4, fq = quad * 8;
  int slice = blockIdx.x & 127;
  int qc = blockIdx.x >> 7;
  int b = slice >> 6, hh = (slice >> 3) & 7, p = slice & 7;
  const ushort* base = (const ushort*)qkvp + (size_t)(b * PPV + p) * NSEQ * QKVW;
  const ushort* kb = base + 512 + hh * DHEAD;
  const ushort* vb = vt + (size_t)slice * 65536;

  int s0 = w * 64 + l, s1 = 256 + w * 64 + l;
  int row0 = s0 >> 3, row1 = s1 >> 3;
  int gc0 = (s0 & 7) ^ (row0 & 7), gc1 = (s1 & 7) ^ (row1 & 7);
  const ushort* kp0 = kb + (size_t)row0 * QKVW + gc0 * 8;
  const ushort* kp1 = kb + (size_t)row1 * QKVW + gc1 * 8;
  const ushort* vp0 = vb + (size_t)row0 * 1024 + gc0 * 8;
  const ushort* vp1 = vb + (size_t)row1 * 1024 + gc1 * 8;

  async_copy16(kp0, &Ks[0][s0 * 8]);
  async_copy16(kp1, &Ks[0][s1 * 8]);
  async_copy16(vp0, &Vs[0][s0 * 8]);
  async_copy16(vp1, &Vs[0][s1 * 8]);

  int q0 = qc * 128 + w * 32;
  short8 qf[2][2];
  #pragma unroll
  for (int mi = 0; mi < 2; mi++)
    #pragma unroll
    for (int kk = 0; kk < 2; kk++)
      qf[mi][kk] = *(const short8*)(base + (size_t)(q0 + mi * 16 + r15) * QKVW + hh * DHEAD + kk * 32 + fq);

  floatx4 o[2][4] = {};
  floatx4 lacc[2] = {};
  short8 ones;
  #pragma unroll
  for (int j = 0; j < 8; j++) ones[j] = (short)0x3F80;

  int sw = r15 & 7;
  int swp = (r15 & 3) << 3;
  ushort* PsW = Ps[w];

  for (int it = 0; it < NSEQ / 64; ++it){
    int cur = it & 1;
    asm volatile("s_waitcnt vmcnt(0)\n\ts_barrier" ::: "memory");
    if (it + 1 < NSEQ / 64){
      int nxt = cur ^ 1;
      kp0 += 64 * QKVW; kp1 += 64 * QKVW; vp0 += 64; vp1 += 64;
      async_copy16(kp0, &Ks[nxt][s0 * 8]);
      async_copy16(kp1, &Ks[nxt][s1 * 8]);
      async_copy16(vp0, &Vs[nxt][s0 * 8]);
      async_copy16(vp1, &Vs[nxt][s1 * 8]);
    }
    const ushort* Kb = Ks[cur];
    const ushort* Vb = Vs[cur];

    short8 pf[2][2];
    #pragma unroll
    for (int kk = 0; kk < 2; kk++){
      #pragma unroll
      for (int nn = 0; nn < 2; nn++){
        int ni = kk * 2 + nn;
        int rb2 = (ni * 16 + r15) * 64;
        short8 kf0 = *(const short8*)&Kb[rb2 + (quad ^ sw) * 8];
        short8 kf1 = *(const short8*)&Kb[rb2 + ((4 + quad) ^ sw) * 8];
        floatx4 sA = {}, sB = {};
        sA = __builtin_amdgcn_mfma_f32_16x16x32_bf16(kf0, qf[0][0], sA, 0, 0, 0);
        sA = __builtin_amdgcn_mfma_f32_16x16x32_bf16(kf1, qf[0][1], sA, 0, 0, 0);
        sB = __builtin_amdgcn_mfma_f32_16x16x32_bf16(kf0, qf[1][0], sB, 0, 0, 0);
        sB = __builtin_amdgcn_mfma_f32_16x16x32_bf16(kf1, qf[1][1], sB, 0, 0, 0);
        int wc = (nn * 16 + quad * 4) ^ swp;
        union { float f; uint u; } e0, e1, e2, e3;
        uint2 pk;
        e0.f = exp2f(sA[0]); e1.f = exp2f(sA[1]);
        e2.f = exp2f(sA[2]); e3.f = exp2f(sA[3]);
        pk.x = __builtin_amdgcn_perm(e1.u, e0.u, 0x07060302u);
        pk.y = __builtin_amdgcn_perm(e3.u, e2.u, 0x07060302u);
        *(uint2*)&PsW[r15 * 32 + wc] = pk;
        e0.f = exp2f(sB[0]); e1.f = exp2f(sB[1]);
        e2.f = exp2f(sB[2]); e3.f = exp2f(sB[3]);
        pk.x = __builtin_amdgcn_perm(e1.u, e0.u, 0x07060302u);
        pk.y = __builtin_amdgcn_perm(e3.u, e2.u, 0x07060302u);
        *(uint2*)&PsW[(16 + r15) * 32 + wc] = pk;
      }
      asm volatile("s_waitcnt lgkmcnt(0)" ::: "memory");
      pf[0][kk] = *(const short8*)&PsW[r15 * 32 + (fq ^ swp)];
      pf[1][kk] = *(const short8*)&PsW[(16 + r15) * 32 + (fq ^ swp)];
      asm volatile("s_waitcnt lgkmcnt(0)" ::: "memory");
    }

    #pragma unroll
    for (int mi = 0; mi < 2; mi++)
      #pragma unroll
      for (int kk = 0; kk < 2; kk++)
        lacc[mi] = __builtin_amdgcn_mfma_f32_16x16x32_bf16(ones, pf[mi][kk], lacc[mi], 0, 0, 0);

    #pragma unroll
    for (int dj = 0; dj < 4; dj++){
      int d = dj * 16 + r15;
      short8 vf0 = *(const short8*)&Vb[d * 64 + ((quad) ^ sw) * 8];
      short8 vf1 = *(const short8*)&Vb[d * 64 + ((4 + quad) ^ sw) * 8];
      #pragma unroll
      for (int mi = 0; mi < 2; mi++){
        o[mi][dj] = __builtin_amdgcn_mfma_f32_16x16x32_bf16(vf0, pf[mi][0], o[mi][dj], 0, 0, 0);
        o[mi][dj] = __builtin_amdgcn_mfma_f32_16x16x32_bf16(vf1, pf[mi][1], o[mi][dj], 0, 0, 0);
      }
    }
  }

  #pragma unroll
  for (int mi = 0; mi < 2; mi++){
    float inv = __builtin_amdgcn_rcpf(lacc[mi][0]);
    size_t n = q0 + mi * 16 + r15;
    ushort* orow = (ushort*)outp + ((size_t)((b * HEADSV + hh) * NSEQ + n)) * DIMV + p * DHEAD + quad * 4;
    #pragma unroll
    for (int dj = 0; dj < 4; dj++){
      ushortx4 ov;
      #pragma unroll
      for (int r = 0; r < 4; r++) ov[r] = f2bf(o[mi][dj][r] * inv);
      *(ushortx4*)(orow + dj * 16) = ov;
    }
  }
}

extern "C" void kernel_launch(void* const* d_in, const int* in_sizes, int n_in,
                              void* d_out, int out_size, void* d_ws, size_t ws_size,
                              hipStream_t stream){
  (void)in_sizes; (void)n_in; (void)out_size; (void)ws_size;
  const float* x    = (const float*)d_in[0];
  const float* lw0  = (const float*)d_in[1];
  const float* lb0  = (const float*)d_in[2];
  const float* lw1  = (const float*)d_in[3];
  const float* lb1  = (const float*)d_in[4];
  const float* wqkv = (const float*)d_in[5];
  const float* wo   = (const float*)d_in[6];
  const float* bo   = (const float*)d_in[7];
  const float* w1   = (const float*)d_in[8];
  const float* b1   = (const float*)d_in[9];
  const float* w2   = (const float*)d_in[10];
  const float* b2   = (const float*)d_in[11];
  float* out = (float*)d_out;
  char* ws = (char*)d_ws;
  const size_t MB = 1024 * 1024;

  __hip_bfloat16* x1b  = (__hip_bfloat16*)(ws);
  ushort* vtbuf        = (ushort*)(ws + 32 * MB);
  __hip_bfloat16* x2b  = (__hip_bfloat16*)(ws + 64 * MB);
  __hip_bfloat16* wqkvT= (__hip_bfloat16*)(ws + 80 * MB);
  __hip_bfloat16* woT  = (__hip_bfloat16*)(ws + 82 * MB);
  __hip_bfloat16* w1T  = (__hip_bfloat16*)(ws + 83 * MB);
  __hip_bfloat16* w2T  = (__hip_bfloat16*)(ws + 85 * MB);
  __hip_bfloat16* hB   = (__hip_bfloat16*)(ws + 88 * MB);
  __hip_bfloat16* attnB= hB;
  __hip_bfloat16* qkvB = (__hip_bfloat16*)(ws + 104 * MB);
  __hip_bfloat16* tB   = (__hip_bfloat16*)(ws + 88 * MB);

  // 1) fused prep: LN (16384 blocks) + 4 weight transposes (3072 blocks)
  prep_kernel<<<NTOK + 3072, 256, 0, stream>>>(
      x, lw0, lb0, lw1, lb1, x1b, hB,
      wqkv, wqkvT, wo, woT, w1, w1T, w2, w2T);

  // 2) qkv = h @ w_qkv -> bf16 (Q scaled by SC2, K) + transposed V into vtbuf
  //    256^2 kernel: grid (16384/256)x(1536/256) = 64x6 = 384
  gemm_8p<0><<<384, 512, 0, stream>>>(
      hB, wqkvT, nullptr, qkvB, vtbuf, NTOK, QKVW, DIMV, 6, 0);

  // 3) attention
  attn_mfma<<<1024, 256, 0, stream>>>(qkvB, vtbuf, attnB);

  // 4) x2b = attn @ w_o + b_o + x1b -> bf16 (N=512: keep 128^2 kernel)
  gemm_mfma<1><<<(DIMV / 128) * 128, 256, 0, stream>>>(
      attnB, woT, bo, x1b, nullptr, x2b, nullptr,
      NTOK, DIMV, DIMV, DIMV / 128, 0);

  // 5) t = gelu_fast(x2b @ w1 + b1) -> bf16
  //    256^2 kernel: grid 64x8 = 512
  gemm_8p<1><<<512, 512, 0, stream>>>(
      x2b, w1T, b1, tB, nullptr, NTOK, HIDV, DIMV, 8, 1);

  // 6) out = t @ w2 + b2 + x2b -> fp32 (N=512: keep 128^2 kernel)
  gemm_mfma<1><<<(DIMV / 128) * 128, 256, 0, stream>>>(
      tB, w2T, b2, x2b, out, nullptr, nullptr,
      NTOK, DIMV, HIDV, DIMV / 128, 0);
}

// Round 10
// 341.387 us; speedup vs baseline: 1.0757x; 1.0339x over previous
//
#include <hip/hip_runtime.h>
#include <hip/hip_bf16.h>
#include <math.h>

#define DIMV 512
#define NTOK 16384   // B*P*N = 2*8*1024
#define NSEQ 1024
#define HEADSV 8
#define PPV 8
#define DHEAD 64
#define QKVW 1536
#define HIDV 2048
#define SC2 0.18033688011112042f   // 0.125 * log2(e)

typedef unsigned short ushort;
typedef unsigned int uint;
typedef __attribute__((ext_vector_type(8))) short short8;
typedef __attribute__((ext_vector_type(8))) unsigned short ushort8;
typedef __attribute__((ext_vector_type(4))) unsigned short ushortx4;
typedef __attribute__((ext_vector_type(4))) float floatx4;

__device__ __forceinline__ float bf2f(ushort u){
  union { unsigned int i; float f; } c; c.i = ((unsigned int)u) << 16; return c.f;
}
// fast RNE f32->bf16 (finite values; no NaN branch): 3 VALU
__device__ __forceinline__ ushort f2bf(float f){
  union { float f; unsigned int i; } c; c.f = f;
  unsigned int u = c.i + 0x7fffu + ((c.i >> 16) & 1u);
  return (ushort)(u >> 16);
}
__device__ __forceinline__ void async_copy16(const void* gptr, void* lptr){
  __builtin_amdgcn_global_load_lds((const __attribute__((address_space(1))) void*)gptr,
                                   (__attribute__((address_space(3))) void*)lptr, 16, 0, 0);
}
// tanh-form GELU via one v_exp_f32: x * sigmoid(1.5957691x + 0.0713548x^3)
__device__ __forceinline__ float fast_gelu(float x){
  float u = x * (2.3022084f + 0.1029435f * x * x);   // (2u)*log2(e)
  return x * __builtin_amdgcn_rcpf(1.f + exp2f(-u));
}

__device__ __forceinline__ void wave_reduce2(float& a, float& b){
  #pragma unroll
  for (int off = 32; off > 0; off >>= 1){
    a += __shfl_down(a, off, 64);
    b += __shfl_down(b, off, 64);
  }
}

// ---- fused prep kernel: LN (2 rows/block, blocks [0,8192)) + transposes ----
__device__ __forceinline__ void wtrans_body(const float* __restrict__ W,
    __hip_bfloat16* __restrict__ Wt, int K, int N, int bx, int by, int t,
    float* tile /* 32*33 */){
  int bn = bx * 32, bk = by * 32;
  int tx = t & 31, ty = t >> 5;
  #pragma unroll
  for (int i = 0; i < 32; i += 8)
    tile[(ty + i) * 33 + tx] = W[(size_t)(bk + ty + i) * N + bn + tx];
  __syncthreads();
  #pragma unroll
  for (int i = 0; i < 32; i += 8)
    Wt[(size_t)(bn + ty + i) * K + bk + tx] = __float2bfloat16(tile[tx * 33 + ty + i]);
}

__global__ __launch_bounds__(256) void prep_kernel(const float* __restrict__ x,
    const float* __restrict__ w0, const float* __restrict__ b0,
    const float* __restrict__ w1ln, const float* __restrict__ b1ln,
    __hip_bfloat16* __restrict__ x1, __hip_bfloat16* __restrict__ h,
    const float* __restrict__ wqkv, __hip_bfloat16* __restrict__ wqkvT,
    const float* __restrict__ wo,   __hip_bfloat16* __restrict__ woT,
    const float* __restrict__ w1,   __hip_bfloat16* __restrict__ w1T,
    const float* __restrict__ w2,   __hip_bfloat16* __restrict__ w2T){
  __shared__ float smem[32 * 33];
  int bid = blockIdx.x;
  int t = threadIdx.x;
  if (bid >= NTOK / 2){
    int r = bid - NTOK / 2;
    if (r < 768)        wtrans_body(wqkv, wqkvT, 512, 1536, r % 48, r / 48, t, smem);
    else if (r < 1024){ r -= 768;  wtrans_body(wo, woT, 512, 512,  r % 16, r / 16, t, smem); }
    else if (r < 2048){ r -= 1024; wtrans_body(w1, w1T, 512, 2048, r % 64, r / 64, t, smem); }
    else             { r -= 2048; wtrans_body(w2, w2T, 2048, 512, r % 16, r / 16, t, smem); }
    return;
  }
  // ---- double LN, 2 rows per block: threads [0,128) row0, [128,256) row1.
  // float4 loads (16B/lane); per-row stats combine the row's 2 waves via smem.
  float* sm = smem;
  int rh = t >> 7;          // which row half
  int tc = t & 127;
  size_t row = (size_t)bid * 2 + rh;
  float4 v = ((const float4*)(x + row * DIMV))[tc];
  float s = v.x + v.y + v.z + v.w;
  float sq = v.x * v.x + v.y * v.y + v.z * v.z + v.w * v.w;
  wave_reduce2(s, sq);
  int wid = t >> 6, lane = t & 63;   // waves 0-1 -> row0, 2-3 -> row1
  if (lane == 0){ sm[wid] = s; sm[8 + wid] = sq; }
  __syncthreads();
  s  = sm[rh * 2] + sm[rh * 2 + 1];
  sq = sm[8 + rh * 2] + sm[8 + rh * 2 + 1];
  float mu = s * (1.f / DIMV);
  float var = sq * (1.f / DIMV) - mu * mu;
  float r = rsqrtf(var + 1e-5f);
  float4 ww = ((const float4*)w0)[tc];
  float4 bb = ((const float4*)b0)[tc];
  float4 y;
  y.x = (v.x - mu) * r * ww.x + bb.x;
  y.y = (v.y - mu) * r * ww.y + bb.y;
  y.z = (v.z - mu) * r * ww.z + bb.z;
  y.w = (v.w - mu) * r * ww.w + bb.w;
  ushortx4 xb;
  xb[0] = f2bf(y.x); xb[1] = f2bf(y.y); xb[2] = f2bf(y.z); xb[3] = f2bf(y.w);
  *(ushortx4*)((ushort*)x1 + row * DIMV + tc * 4) = xb;
  float s2 = y.x + y.y + y.z + y.w;
  float sq2 = y.x * y.x + y.y * y.y + y.z * y.z + y.w * y.w;
  wave_reduce2(s2, sq2);
  __syncthreads();
  if (lane == 0){ sm[wid] = s2; sm[8 + wid] = sq2; }
  __syncthreads();
  s2  = sm[rh * 2] + sm[rh * 2 + 1];
  sq2 = sm[8 + rh * 2] + sm[8 + rh * 2 + 1];
  float mu2 = s2 * (1.f / DIMV);
  float var2 = sq2 * (1.f / DIMV) - mu2 * mu2;
  float r2 = rsqrtf(var2 + 1e-5f);
  float4 w1v = ((const float4*)w1ln)[tc];
  float4 b1v = ((const float4*)b1ln)[tc];
  ushortx4 hb;
  hb[0] = f2bf((y.x - mu2) * r2 * w1v.x + b1v.x);
  hb[1] = f2bf((y.y - mu2) * r2 * w1v.y + b1v.y);
  hb[2] = f2bf((y.z - mu2) * r2 * w1v.z + b1v.z);
  hb[3] = f2bf((y.w - mu2) * r2 * w1v.w + b1v.w);
  *(ushortx4*)((ushort*)h + row * DIMV + tc * 4) = hb;
}

// ============================================================================
// 256x256 GEMM, v3 schedule (R9 best-measured: 64.4us on w1 — unchanged).
// ============================================================================
template<int SWAP>
__global__ __launch_bounds__(512, 2) void gemm_8p(
    const __hip_bfloat16* __restrict__ A,
    const __hip_bfloat16* __restrict__ Bt,
    const float* __restrict__ bias,
    __hip_bfloat16* __restrict__ Cb,
    ushort* __restrict__ vt,
    int M, int N, int K, int gx, int dogelu)
{
  __shared__ __hip_bfloat16 As[2][256 * 64];
  __shared__ __hip_bfloat16 Bs[2][256 * 64];
  int tid = threadIdx.x;
  int l = tid & 63, w = tid >> 6;
  int wr = w >> 2, wc = w & 3;
  int fm = l & 15, quad = l >> 4;

  int bid = blockIdx.x;
  int xcd = bid & 7, idx = bid >> 3;
  int xl = idx % gx, yl = idx / gx;
  size_t bm = (size_t)(xcd * 8 + yl) * 256;
  size_t bn = (size_t)xl * 256;

  int sr = tid >> 3;
  int sc = ((tid & 7) ^ (sr & 7)) * 8;
  const __hip_bfloat16* Ab0 = A + (bm + sr) * (size_t)K + sc;
  const __hip_bfloat16* Bb0 = Bt + (bn + sr) * (size_t)K + sc;
  int ldst = tid * 8;   // elems; + unit*4096

  int nk = K >> 6;

  // prologue: stage tile 0 into buf 0 (A first — slow loads get max cover)
  #pragma unroll
  for (int j = 0; j < 4; j++)
    async_copy16(Ab0 + (size_t)j * 64 * K, &As[0][j * 4096 + ldst]);
  #pragma unroll
  for (int j = 0; j < 4; j++)
    async_copy16(Bb0 + (size_t)j * 64 * K, &Bs[0][j * 4096 + ldst]);

  floatx4 acc[8][4] = {};

  int arow = wr * 128 + fm;   // + ri*16
  int brow = wc * 64 + fm;    // + ci*16
  int cx = fm & 7;            // read-side chunk XOR key (row&7)

  for (int t = 0; t < nk; ++t){
    int cur = t & 1, nxt = cur ^ 1;
    asm volatile("s_waitcnt vmcnt(0)\n\ts_barrier" ::: "memory");
    if (t + 1 < nk){
      const __hip_bfloat16* Asrc = Ab0 + (size_t)(t + 1) * 64;
      const __hip_bfloat16* Bsrc = Bb0 + (size_t)(t + 1) * 64;
      #pragma unroll
      for (int j = 0; j < 4; j++)
        async_copy16(Asrc + (size_t)j * 64 * K, &As[nxt][j * 4096 + ldst]);
      #pragma unroll
      for (int j = 0; j < 4; j++)
        async_copy16(Bsrc + (size_t)j * 64 * K, &Bs[nxt][j * 4096 + ldst]);
    }
    const __hip_bfloat16* Ac = As[cur];
    const __hip_bfloat16* Bc = Bs[cur];
    short8 bf[4][2];
    #pragma unroll
    for (int ci = 0; ci < 4; ci++)
      #pragma unroll
      for (int kb = 0; kb < 2; kb++)
        bf[ci][kb] = *(const short8*)&Bc[(brow + ci * 16) * 64 + ((kb * 4 + quad) ^ cx) * 8];
    #pragma unroll
    for (int p = 0; p < 4; p++){
      short8 af[2][2];
      #pragma unroll
      for (int i = 0; i < 2; i++)
        #pragma unroll
        for (int kb = 0; kb < 2; kb++)
          af[i][kb] = *(const short8*)&Ac[(arow + (p * 2 + i) * 16) * 64 + ((kb * 4 + quad) ^ cx) * 8];
      #pragma unroll
      for (int i = 0; i < 2; i++)
        #pragma unroll
        for (int ci = 0; ci < 4; ci++)
          #pragma unroll
          for (int kb = 0; kb < 2; kb++){
            if (SWAP)
              acc[p * 2 + i][ci] = __builtin_amdgcn_mfma_f32_16x16x32_bf16(bf[ci][kb], af[i][kb], acc[p * 2 + i][ci], 0, 0, 0);
            else
              acc[p * 2 + i][ci] = __builtin_amdgcn_mfma_f32_16x16x32_bf16(af[i][kb], bf[ci][kb], acc[p * 2 + i][ci], 0, 0, 0);
          }
      if (p == 1)
        asm volatile("s_barrier" ::: "memory");   // scheduling fence only
    }
  }

  // ---- epilogue ----
  if (SWAP){
    #pragma unroll
    for (int ri = 0; ri < 8; ri++){
      size_t row = bm + wr * 128 + ri * 16 + fm;
      size_t rbase = row * (size_t)N + bn + wc * 64 + quad * 4;
      #pragma unroll
      for (int ci = 0; ci < 4; ci++){
        floatx4 v = acc[ri][ci];
        if (bias){
          floatx4 bv = *(const floatx4*)(bias + bn + wc * 64 + ci * 16 + quad * 4);
          #pragma unroll
          for (int r2 = 0; r2 < 4; r2++) v[r2] += bv[r2];
        }
        if (dogelu){
          #pragma unroll
          for (int r2 = 0; r2 < 4; r2++) v[r2] = fast_gelu(v[r2]);
        }
        ushortx4 ob;
        #pragma unroll
        for (int r2 = 0; r2 < 4; r2++) ob[r2] = f2bf(v[r2]);
        *(ushortx4*)((ushort*)Cb + rbase + ci * 16) = ob;
      }
    }
  } else {
    int b = (int)(bm >> 13), p = (int)((bm >> 10) & 7);
    int n0 = (int)(bm & 1023) + wr * 128 + quad * 4;   // + ri*16
    #pragma unroll
    for (int ci = 0; ci < 4; ci++){
      int col = (int)bn + wc * 64 + ci * 16 + fm;
      if (col >= 1024){
        int cc = col - 1024, hh = cc >> 6, dd = cc & 63;
        ushort* vdst = vt + ((size_t)((b * 8 + hh) * 8 + p)) * 65536 + (size_t)dd * 1024 + n0;
        #pragma unroll
        for (int ri = 0; ri < 8; ri++){
          ushortx4 v4;
          v4[0] = f2bf(acc[ri][ci][0]); v4[1] = f2bf(acc[ri][ci][1]);
          v4[2] = f2bf(acc[ri][ci][2]); v4[3] = f2bf(acc[ri][ci][3]);
          *(ushortx4*)(vdst + ri * 16) = v4;
        }
      } else {
        float scl = (col < 512) ? SC2 : 1.f;
        #pragma unroll
        for (int ri = 0; ri < 8; ri++){
          size_t rowb = bm + wr * 128 + ri * 16 + quad * 4;
          #pragma unroll
          for (int r2 = 0; r2 < 4; r2++)
            ((ushort*)Cb)[(rowb + r2) * (size_t)N + col] = f2bf(acc[ri][ci][r2] * scl);
        }
      }
    }
  }
}

// MFMA bf16 GEMM: BK=32, 128x128 tile, XCD-swizzled 1D grid (wo / w2).
// R10: 2-buffer LDS (32KB) + __launch_bounds__(256,4) -> target 4 blocks/CU
// (16 waves/CU, TLP up from ~3 blocks). v3-style loop: ONE vmcnt(0)+barrier
// per K-step; stage of step t+1 issued after the barrier into the buffer
// whose tenant (t-1) was fully consumed before any wave passed barrier t.
template<int SWAP>
__global__ __launch_bounds__(256, 4) void gemm_mfma(
    const __hip_bfloat16* __restrict__ A,
    const __hip_bfloat16* __restrict__ Bt,
    const float* __restrict__ bias,
    const __hip_bfloat16* __restrict__ Rb,
    float* __restrict__ Cf,
    __hip_bfloat16* __restrict__ Cb,
    ushort* __restrict__ vt,
    int M, int N, int K, int gx, int dogelu)
{
  __shared__ __hip_bfloat16 As[2][128 * 32];
  __shared__ __hip_bfloat16 Bs[2][128 * 32];
  int tid = threadIdx.x;
  int w = tid >> 6, l = tid & 63;

  int bid = blockIdx.x;
  int xcd = bid & 7, idx = bid >> 3;
  int xl = idx % gx, yl = idx / gx;
  size_t bm = (size_t)(xcd * 16 + yl) * 128;
  size_t bn = (size_t)xl * 128;
  int wm = (w & 1) * 64, wn = (w >> 1) * 64;

  int srow = w * 16 + (l >> 2);
  int gcs = ((l & 3) ^ (srow & 3)) * 8;
  const __hip_bfloat16* Ag0 = A + (bm + srow) * K + gcs;
  const __hip_bfloat16* Ag1 = A + (bm + 64 + srow) * K + gcs;
  const __hip_bfloat16* Bg0 = Bt + (bn + srow) * K + gcs;
  const __hip_bfloat16* Bg1 = Bt + (bn + 64 + srow) * K + gcs;
  int lo = srow * 32 + (l & 3) * 8;

  floatx4 acc[4][4] = {};
  int fm = l & 15;
  int quad = l >> 4;
  int cs = fm & 3;

  int nk = K >> 5;
  async_copy16(Ag0, &As[0][lo]);
  async_copy16(Ag1, &As[0][lo + 64 * 32]);
  async_copy16(Bg0, &Bs[0][lo]);
  async_copy16(Bg1, &Bs[0][lo + 64 * 32]);

  for (int it = 0; it < nk; ++it){
    int cur = it & 1;
    asm volatile("s_waitcnt vmcnt(0)\n\ts_barrier" ::: "memory");
    if (it + 1 < nk){
      int nb = cur ^ 1;
      int k0 = (it + 1) << 5;
      async_copy16(Ag0 + k0, &As[nb][lo]);
      async_copy16(Ag1 + k0, &As[nb][lo + 64 * 32]);
      async_copy16(Bg0 + k0, &Bs[nb][lo]);
      async_copy16(Bg1 + k0, &Bs[nb][lo + 64 * 32]);
    }
    const __hip_bfloat16* Ab = As[cur];
    const __hip_bfloat16* Bb = Bs[cur];
    short8 af[4], bf[4];
    #pragma unroll
    for (int i = 0; i < 4; i++){
      af[i] = *(const short8*)&Ab[(wm + i * 16 + fm) * 32 + ((quad ^ cs) * 8)];
      bf[i] = *(const short8*)&Bb[(wn + i * 16 + fm) * 32 + ((quad ^ cs) * 8)];
    }
    #pragma unroll
    for (int mi = 0; mi < 4; mi++)
      #pragma unroll
      for (int ni = 0; ni < 4; ni++){
        if (SWAP)
          acc[mi][ni] = __builtin_amdgcn_mfma_f32_16x16x32_bf16(bf[ni], af[mi], acc[mi][ni], 0, 0, 0);
        else
          acc[mi][ni] = __builtin_amdgcn_mfma_f32_16x16x32_bf16(af[mi], bf[ni], acc[mi][ni], 0, 0, 0);
      }
  }

  int rq = quad * 4;
  if (SWAP){
    #pragma unroll
    for (int mi = 0; mi < 4; mi++){
      size_t row = bm + wm + mi * 16 + fm;
      size_t rbase = row * (size_t)N + bn + wn + rq;
      #pragma unroll
      for (int ni = 0; ni < 4; ni++){
        size_t idx2 = rbase + ni * 16;
        floatx4 v = acc[mi][ni];
        if (bias){
          floatx4 bv = *(const floatx4*)(bias + bn + wn + ni * 16 + rq);
          #pragma unroll
          for (int r2 = 0; r2 < 4; r2++) v[r2] += bv[r2];
        }
        if (dogelu){
          #pragma unroll
          for (int r2 = 0; r2 < 4; r2++) v[r2] = fast_gelu(v[r2]);
        }
        if (Rb){
          ushortx4 rbv = *(const ushortx4*)((const ushort*)Rb + idx2);
          #pragma unroll
          for (int r2 = 0; r2 < 4; r2++) v[r2] += bf2f(rbv[r2]);
        }
        if (Cb){
          ushortx4 ob;
          #pragma unroll
          for (int r2 = 0; r2 < 4; r2++) ob[r2] = f2bf(v[r2]);
          *(ushortx4*)((ushort*)Cb + idx2) = ob;
        } else {
          *(floatx4*)(Cf + idx2) = v;
        }
      }
    }
  } else {
    #pragma unroll
    for (int ni = 0; ni < 4; ni++){
      size_t col = bn + wn + ni * 16 + fm;
      float bv = bias ? bias[col] : 0.f;
      #pragma unroll
      for (int mi = 0; mi < 4; mi++){
        #pragma unroll
        for (int r2 = 0; r2 < 4; r2++){
          size_t row = bm + wm + mi * 16 + rq + r2;
          float v = acc[mi][ni][r2] + bv;
          if (dogelu) v = fast_gelu(v);
          size_t idx2 = row * N + col;
          if (Rb) v += bf2f(((const ushort*)Rb)[idx2]);
          Cf[idx2] = v;
        }
      }
    }
  }
}

// MFMA flash attention (round-6 verified, unchanged). Q pre-scaled by SC2.
__global__ __launch_bounds__(256, 4) void attn_mfma(const __hip_bfloat16* __restrict__ qkvp,
                                                    const ushort* __restrict__ vt,
                                                    __hip_bfloat16* __restrict__ outp){
  __shared__ ushort Ks[2][64 * 64];
  __shared__ ushort Vs[2][64 * 64];
  __shared__ ushort Ps[4][32 * 32];
  int tid = threadIdx.x;
  int w = tid >> 6, l = tid & 63;
  int r15 = l & 15, quad = l >> 4, fq = quad * 8;
  int slice = blockIdx.x & 127;
  int qc = blockIdx.x >> 7;
  int b = slice >> 6, hh = (slice >> 3) & 7, p = slice & 7;
  const ushort* base = (const ushort*)qkvp + (size_t)(b * PPV + p) * NSEQ * QKVW;
  const ushort* kb = base + 512 + hh * DHEAD;
  const ushort* vb = vt + (size_t)slice * 65536;

  int s0 = w * 64 + l, s1 = 256 + w * 64 + l;
  int row0 = s0 >> 3, row1 = s1 >> 3;
  int gc0 = (s0 & 7) ^ (row0 & 7), gc1 = (s1 & 7) ^ (row1 & 7);
  const ushort* kp0 = kb + (size_t)row0 * QKVW + gc0 * 8;
  const ushort* kp1 = kb + (size_t)row1 * QKVW + gc1 * 8;
  const ushort* vp0 = vb + (size_t)row0 * 1024 + gc0 * 8;
  const ushort* vp1 = vb + (size_t)row1 * 1024 + gc1 * 8;

  async_copy16(kp0, &Ks[0][s0 * 8]);
  async_copy16(kp1, &Ks[0][s1 * 8]);
  async_copy16(vp0, &Vs[0][s0 * 8]);
  async_copy16(vp1, &Vs[0][s1 * 8]);

  int q0 = qc * 128 + w * 32;
  short8 qf[2][2];
  #pragma unroll
  for (int mi = 0; mi < 2; mi++)
    #pragma unroll
    for (int kk = 0; kk < 2; kk++)
      qf[mi][kk] = *(const short8*)(base + (size_t)(q0 + mi * 16 + r15) * QKVW + hh * DHEAD + kk * 32 + fq);

  floatx4 o[2][4] = {};
  floatx4 lacc[2] = {};
  short8 ones;
  #pragma unroll
  for (int j = 0; j < 8; j++) ones[j] = (short)0x3F80;

  int sw = r15 & 7;
  int swp = (r15 & 3) << 3;
  ushort* PsW = Ps[w];

  for (int it = 0; it < NSEQ / 64; ++it){
    int cur = it & 1;
    asm volatile("s_waitcnt vmcnt(0)\n\ts_barrier" ::: "memory");
    if (it + 1 < NSEQ / 64){
      int nxt = cur ^ 1;
      kp0 += 64 * QKVW; kp1 += 64 * QKVW; vp0 += 64; vp1 += 64;
      async_copy16(kp0, &Ks[nxt][s0 * 8]);
      async_copy16(kp1, &Ks[nxt][s1 * 8]);
      async_copy16(vp0, &Vs[nxt][s0 * 8]);
      async_copy16(vp1, &Vs[nxt][s1 * 8]);
    }
    const ushort* Kb = Ks[cur];
    const ushort* Vb = Vs[cur];

    short8 pf[2][2];
    #pragma unroll
    for (int kk = 0; kk < 2; kk++){
      #pragma unroll
      for (int nn = 0; nn < 2; nn++){
        int ni = kk * 2 + nn;
        int rb2 = (ni * 16 + r15) * 64;
        short8 kf0 = *(const short8*)&Kb[rb2 + (quad ^ sw) * 8];
        short8 kf1 = *(const short8*)&Kb[rb2 + ((4 + quad) ^ sw) * 8];
        floatx4 sA = {}, sB = {};
        sA = __builtin_amdgcn_mfma_f32_16x16x32_bf16(kf0, qf[0][0], sA, 0, 0, 0);
        sA = __builtin_amdgcn_mfma_f32_16x16x32_bf16(kf1, qf[0][1], sA, 0, 0, 0);
        sB = __builtin_amdgcn_mfma_f32_16x16x32_bf16(kf0, qf[1][0], sB, 0, 0, 0);
        sB = __builtin_amdgcn_mfma_f32_16x16x32_bf16(kf1, qf[1][1], sB, 0, 0, 0);
        int wc = (nn * 16 + quad * 4) ^ swp;
        union { float f; uint u; } e0, e1, e2, e3;
        uint2 pk;
        e0.f = exp2f(sA[0]); e1.f = exp2f(sA[1]);
        e2.f = exp2f(sA[2]); e3.f = exp2f(sA[3]);
        pk.x = __builtin_amdgcn_perm(e1.u, e0.u, 0x07060302u);
        pk.y = __builtin_amdgcn_perm(e3.u, e2.u, 0x07060302u);
        *(uint2*)&PsW[r15 * 32 + wc] = pk;
        e0.f = exp2f(sB[0]); e1.f = exp2f(sB[1]);
        e2.f = exp2f(sB[2]); e3.f = exp2f(sB[3]);
        pk.x = __builtin_amdgcn_perm(e1.u, e0.u, 0x07060302u);
        pk.y = __builtin_amdgcn_perm(e3.u, e2.u, 0x07060302u);
        *(uint2*)&PsW[(16 + r15) * 32 + wc] = pk;
      }
      asm volatile("s_waitcnt lgkmcnt(0)" ::: "memory");
      pf[0][kk] = *(const short8*)&PsW[r15 * 32 + (fq ^ swp)];
      pf[1][kk] = *(const short8*)&PsW[(16 + r15) * 32 + (fq ^ swp)];
      asm volatile("s_waitcnt lgkmcnt(0)" ::: "memory");
    }

    #pragma unroll
    for (int mi = 0; mi < 2; mi++)
      #pragma unroll
      for (int kk = 0; kk < 2; kk++)
        lacc[mi] = __builtin_amdgcn_mfma_f32_16x16x32_bf16(ones, pf[mi][kk], lacc[mi], 0, 0, 0);

    #pragma unroll
    for (int dj = 0; dj < 4; dj++){
      int d = dj * 16 + r15;
      short8 vf0 = *(const short8*)&Vb[d * 64 + ((quad) ^ sw) * 8];
      short8 vf1 = *(const short8*)&Vb[d * 64 + ((4 + quad) ^ sw) * 8];
      #pragma unroll
      for (int mi = 0; mi < 2; mi++){
        o[mi][dj] = __builtin_amdgcn_mfma_f32_16x16x32_bf16(vf0, pf[mi][0], o[mi][dj], 0, 0, 0);
        o[mi][dj] = __builtin_amdgcn_mfma_f32_16x16x32_bf16(vf1, pf[mi][1], o[mi][dj], 0, 0, 0);
      }
    }
  }

  #pragma unroll
  for (int mi = 0; mi < 2; mi++){
    float inv = __builtin_amdgcn_rcpf(lacc[mi][0]);
    size_t n = q0 + mi * 16 + r15;
    ushort* orow = (ushort*)outp + ((size_t)((b * HEADSV + hh) * NSEQ + n)) * DIMV + p * DHEAD + quad * 4;
    #pragma unroll
    for (int dj = 0; dj < 4; dj++){
      ushortx4 ov;
      #pragma unroll
      for (int r = 0; r < 4; r++) ov[r] = f2bf(o[mi][dj][r] * inv);
      *(ushortx4*)(orow + dj * 16) = ov;
    }
  }
}

extern "C" void kernel_launch(void* const* d_in, const int* in_sizes, int n_in,
                              void* d_out, int out_size, void* d_ws, size_t ws_size,
                              hipStream_t stream){
  (void)in_sizes; (void)n_in; (void)out_size; (void)ws_size;
  const float* x    = (const float*)d_in[0];
  const float* lw0  = (const float*)d_in[1];
  const float* lb0  = (const float*)d_in[2];
  const float* lw1  = (const float*)d_in[3];
  const float* lb1  = (const float*)d_in[4];
  const float* wqkv = (const float*)d_in[5];
  const float* wo   = (const float*)d_in[6];
  const float* bo   = (const float*)d_in[7];
  const float* w1   = (const float*)d_in[8];
  const float* b1   = (const float*)d_in[9];
  const float* w2   = (const float*)d_in[10];
  const float* b2   = (const float*)d_in[11];
  float* out = (float*)d_out;
  char* ws = (char*)d_ws;
  const size_t MB = 1024 * 1024;

  __hip_bfloat16* x1b  = (__hip_bfloat16*)(ws);
  ushort* vtbuf        = (ushort*)(ws + 32 * MB);
  __hip_bfloat16* x2b  = (__hip_bfloat16*)(ws + 64 * MB);
  __hip_bfloat16* wqkvT= (__hip_bfloat16*)(ws + 80 * MB);
  __hip_bfloat16* woT  = (__hip_bfloat16*)(ws + 82 * MB);
  __hip_bfloat16* w1T  = (__hip_bfloat16*)(ws + 83 * MB);
  __hip_bfloat16* w2T  = (__hip_bfloat16*)(ws + 85 * MB);
  __hip_bfloat16* hB   = (__hip_bfloat16*)(ws + 88 * MB);
  __hip_bfloat16* attnB= hB;
  __hip_bfloat16* qkvB = (__hip_bfloat16*)(ws + 104 * MB);
  __hip_bfloat16* tB   = (__hip_bfloat16*)(ws + 88 * MB);

  // 1) fused prep: LN (8192 blocks x 2 rows) + 4 weight transposes (3072)
  prep_kernel<<<NTOK / 2 + 3072, 256, 0, stream>>>(
      x, lw0, lb0, lw1, lb1, x1b, hB,
      wqkv, wqkvT, wo, woT, w1, w1T, w2, w2T);

  // 2) qkv = h @ w_qkv -> bf16 (Q scaled by SC2, K) + transposed V into vtbuf
  gemm_8p<0><<<384, 512, 0, stream>>>(
      hB, wqkvT, nullptr, qkvB, vtbuf, NTOK, QKVW, DIMV, 6, 0);

  // 3) attention
  attn_mfma<<<1024, 256, 0, stream>>>(qkvB, vtbuf, attnB);

  // 4) x2b = attn @ w_o + b_o + x1b -> bf16 (N=512: 128^2 kernel, 2-buf)
  gemm_mfma<1><<<(DIMV / 128) * 128, 256, 0, stream>>>(
      attnB, woT, bo, x1b, nullptr, x2b, nullptr,
      NTOK, DIMV, DIMV, DIMV / 128, 0);

  // 5) t = gelu_fast(x2b @ w1 + b1) -> bf16 (256^2 kernel)
  gemm_8p<1><<<512, 512, 0, stream>>>(
      x2b, w1T, b1, tB, nullptr, NTOK, HIDV, DIMV, 8, 1);

  // 6) out = t @ w2 + b2 + x2b -> fp32 (N=512: 128^2 kernel, 2-buf)
  gemm_mfma<1><<<(DIMV / 128) * 128, 256, 0, stream>>>(
      tB, w2T, b2, x2b, out, nullptr, nullptr,
      NTOK, DIMV, HIDV, DIMV / 128, 0);
}